// Round 5
// baseline (422.671 us; speedup 1.0000x reference)
//
#include <hip/hip_runtime.h>
#include <hip/hip_bf16.h>
#include <stdint.h>

using bf16 = __hip_bfloat16;
typedef __attribute__((ext_vector_type(8))) short bf16x8;
typedef __attribute__((ext_vector_type(4))) float f32x4;

#define NN 50000
#define NE 400000
#define NG 64
#define FIN 64
#define HID 96
#define CC3 64
#define NOUT 10

#define SCAN_BLOCK 256
#define NPART ((NN + SCAN_BLOCK - 1) / SCAN_BLOCK)   // 196 (<=256)

__device__ __forceinline__ float b2f(bf16 h){ return __bfloat162float(h); }
__device__ __forceinline__ bf16 f2b(float f){ return __float2bfloat16(f); }
__device__ __forceinline__ float blo(unsigned v){ return __uint_as_float(v << 16); }
__device__ __forceinline__ float bhi(unsigned v){ return __uint_as_float(v & 0xFFFF0000u); }

// ============ prep_a: logit folds, folded-logit tile for layer 1, zero fills ========
struct PrepA {
  const float *Wm1,*att1,*bm1,*Wm2,*att2,*bm2,*Wm3,*att3,*bm3,*bs1;
  float *f2,*f3,*lbv,*zb; bf16* WTf1;
  int* deg; float* psum; int* done;
};
__global__ __launch_bounds__(256) void prep_a_kernel(PrepA j){
  int bid = blockIdx.x;
  if (bid == 0){
    for (int i=threadIdx.x; i<96*4; i+=256){
      int k=i>>2, h=i&3; float a=0.f;
      for (int c=0;c<96;++c) a += j.Wm2[k*384 + h*96 + c]*j.att2[h*96+c];
      j.f2[i]=a;
    }
    for (int i=threadIdx.x; i<96*4; i+=256){
      int k=i>>2, h=i&3; float a=0.f;
      for (int c=0;c<64;++c) a += j.Wm3[k*256 + h*64 + c]*j.att3[h*64+c];
      j.f3[i]=a;
    }
    for (int i=threadIdx.x; i<16*64; i+=256){
      int col=i>>6, k=i&63; float a=0.f;
      if (col<4){ for (int c=0;c<96;++c) a += j.Wm1[k*384 + col*96 + c]*j.att1[col*96+c]; }
      j.WTf1[i] = f2b(a);
    }
    if (threadIdx.x < 96) j.zb[threadIdx.x] = 0.f;
    __syncthreads();
    if (threadIdx.x < 4){
      int h = threadIdx.x;
      float l1=0.f,l2=0.f,l3=0.f;
      for (int c=0;c<96;++c) l1 += j.bm1[h*96+c]*j.att1[h*96+c];
      for (int c=0;c<96;++c) l2 += j.bm2[h*96+c]*j.att2[h*96+c];
      for (int c=0;c<64;++c) l3 += j.bm3[h*64+c]*j.att3[h*64+c];
      float e2 = l2;
      for (int k=0;k<96;++k) e2 += j.bs1[k]*j.f2[k*4+h];
      j.lbv[h]=l1; j.lbv[4+h]=e2; j.lbv[8+h]=l3;
    }
  } else if (bid <= NPART){
    int i=(bid-1)*256+threadIdx.x;
    if (i<NN) j.deg[i]=0;
  } else {
    for (int i=threadIdx.x; i<NG*CC3; i+=256) j.psum[i]=0.f;
    if (threadIdx.x==0) *j.done = 0;
  }
}

// ============ prep_b: combined transposed weight matrices (with logit folds) ========
struct PrepB {
  const float *Wm1,*bm1,*Ws1,*Wm2,*bm2,*Wm3,*bm3,*Ws3;
  const float *f2,*f3;
  bf16 *WT1,*WT2,*WT3;
};
__device__ __forceinline__ float w1full(const PrepB& j, int k, int c){
  if (k < 256) return 0.25f*j.Wm1[(k&63)*384 + (k>>6)*96 + c];
  if (k == 256) return 0.25f*(j.bm1[c]+j.bm1[96+c]+j.bm1[192+c]+j.bm1[288+c]);
  if (k < 288) return 0.f;
  return j.Ws1[(k-288)*96 + c];
}
__device__ __forceinline__ float w2full(const PrepB& j, int k, int c){
  if (k < 384){ int kk=k%96, h=k/96; return 0.25f*j.Wm2[kk*384 + h*96 + c]; }
  if (k == 384) return 0.25f*(j.bm2[c]+j.bm2[96+c]+j.bm2[192+c]+j.bm2[288+c]);
  if (k < 416) return 0.f;
  return (k-416==c) ? 1.f : 0.f;
}
__device__ __forceinline__ float w3full(const PrepB& j, int k, int c){
  if (k < 384){ int kk=k%96, h=k/96; return 0.25f*j.Wm3[kk*256 + h*64 + c]; }
  if (k == 384) return 0.25f*(j.bm3[c]+j.bm3[64+c]+j.bm3[128+c]+j.bm3[192+c]);
  if (k < 416) return 0.f;
  return j.Ws3[(k-416)*64 + c];
}
__global__ __launch_bounds__(256) void prep_b_kernel(PrepB j){
  int idx = blockIdx.x*256 + threadIdx.x;
  if (idx < 112*352){
    int col = idx/352, k = idx - col*352;
    float v;
    if (col < 96) v = w1full(j,k,col);
    else if (col < 100){ int h=col-96; float a=0.f;
      for (int c=0;c<96;++c) a += w1full(j,k,c)*j.f2[c*4+h]; v=a; }
    else v = 0.f;
    j.WT1[col*352 + k] = f2b(v);
  } else if (idx < 112*352 + 112*512){
    int r = idx - 112*352;
    int col = r/512, k = r - col*512;
    float v;
    if (col < 96) v = w2full(j,k,col);
    else if (col < 100){ int h=col-96; float a=0.f;
      for (int c=0;c<96;++c) a += w2full(j,k,c)*j.f3[c*4+h]; v=a; }
    else v = 0.f;
    j.WT2[col*512 + k] = f2b(v);
  } else {
    int r = idx - 112*352 - 112*512;
    int col = r/512, k = r - col*512;
    j.WT3[col*512 + k] = f2b(w3full(j,k,col));
  }
}

// ---------------- CSR build (unchanged, proven) ----------------
__global__ void deg_kernel(const int* __restrict__ ei, int* __restrict__ deg){
  int e = blockIdx.x*256 + threadIdx.x;
  if (e < NE) atomicAdd(&deg[ei[NE + e]], 1);
}

__global__ __launch_bounds__(256) void scan_part_kernel(const int* __restrict__ deg,
    int* __restrict__ partials, int* __restrict__ done, int* __restrict__ off){
  __shared__ int ws[4];
  __shared__ int lastflag;
  __shared__ int buf[256];
  int i = blockIdx.x*SCAN_BLOCK + threadIdx.x;
  int v = (i < NN) ? deg[i] : 0;
  int lane = threadIdx.x & 63, w = threadIdx.x >> 6;
  int s = v;
  #pragma unroll
  for (int m=1;m<64;m<<=1) s += __shfl_xor(s,m);
  if (lane==0) ws[w]=s;
  __syncthreads();
  if (threadIdx.x==0){
    int tot = ws[0]+ws[1]+ws[2]+ws[3];
    atomicExch(&partials[blockIdx.x], tot);
    __threadfence();
    int old = atomicAdd(done, 1);
    lastflag = (old == NPART-1) ? 1 : 0;
  }
  __syncthreads();
  if (lastflag){
    int t = threadIdx.x;
    int pv = (t < NPART) ? atomicAdd(&partials[t], 0) : 0;
    buf[t] = pv; __syncthreads();
    for (int st=1; st<256; st<<=1){
      int x = (t>=st) ? buf[t-st] : 0;
      __syncthreads();
      buf[t] += x;
      __syncthreads();
    }
    if (t < NPART) atomicExch(&partials[t], buf[t] - pv);
    if (t == 0) off[NN] = buf[255];
  }
}

__global__ __launch_bounds__(256) void scan_final_kernel(const int* __restrict__ deg,
    const int* __restrict__ partials, int* __restrict__ off, int* __restrict__ cursor){
  __shared__ int buf[256];
  int i = blockIdx.x*SCAN_BLOCK + threadIdx.x;
  int t = threadIdx.x;
  int v = (i<NN) ? deg[i] : 0;
  buf[t] = v; __syncthreads();
  for (int s=1;s<256;s<<=1){
    int x = (t>=s) ? buf[t-s] : 0;
    __syncthreads();
    buf[t] += x;
    __syncthreads();
  }
  int ex = partials[blockIdx.x] + buf[t] - v;
  if (i<NN){ off[i]=ex; cursor[i]=ex; }
}

__global__ void scatter_kernel(const int* __restrict__ ei, int* __restrict__ cursor,
                               int* __restrict__ csr_src){
  int e = blockIdx.x*256 + threadIdx.x;
  if (e < NE){
    int d = ei[NE + e];
    int slot = atomicAdd(&cursor[d], 1);
    csr_src[slot] = ei[e];
  }
}

// ============ layer-1 front: bf16 copy of x + EL1 via folded-logit MFMA =============
__global__ __launch_bounds__(256) void el1_kernel(const float* __restrict__ x,
    const bf16* __restrict__ WTf1, const float* __restrict__ lbv,
    bf16* __restrict__ xb, float* __restrict__ EL)
{
  const int wave = threadIdx.x>>6, lane = threadIdx.x&63;
  const int tile = blockIdx.x*4 + wave;
  if (tile >= NN/16) return;
  const int lm = lane&15, q = lane>>4;
  const size_t row = (size_t)tile*16 + lm;
  bf16x8 xf[2];
  #pragma unroll
  for (int kt=0;kt<2;++kt){
    float4 a0 = *(const float4*)(x + row*64 + kt*32 + q*8);
    float4 a1 = *(const float4*)(x + row*64 + kt*32 + q*8 + 4);
    bf16 t[8] = {f2b(a0.x),f2b(a0.y),f2b(a0.z),f2b(a0.w),
                 f2b(a1.x),f2b(a1.y),f2b(a1.z),f2b(a1.w)};
    xf[kt] = *(const bf16x8*)t;
    *(bf16x8*)(xb + row*64 + kt*32 + q*8) = xf[kt];
  }
  f32x4 acc = {};
  #pragma unroll
  for (int kt=0;kt<2;++kt){
    bf16x8 wf = *(const bf16x8*)(WTf1 + (size_t)lm*64 + kt*32 + q*8);
    acc = __builtin_amdgcn_mfma_f32_16x16x32_bf16(wf, xf[kt], acc, 0,0,0);
  }
  if (q==0){
    float4 e; float l;
    l=acc[0]+lbv[0]; l=(l>=0.f)?l:0.2f*l; e.x=__expf(fminf(fmaxf(l,-60.f),60.f));
    l=acc[1]+lbv[1]; l=(l>=0.f)?l:0.2f*l; e.y=__expf(fminf(fmaxf(l,-60.f),60.f));
    l=acc[2]+lbv[2]; l=(l>=0.f)?l:0.2f*l; e.z=__expf(fminf(fmaxf(l,-60.f),60.f));
    l=acc[3]+lbv[3]; l=(l>=0.f)?l:0.2f*l; e.w=__expf(fminf(fmaxf(l,-60.f),60.f));
    *(float4*)(EL + 4*row) = e;
  }
}

// ============ fused conv + GEMM: 8 waves, 2 nodes/wave, vector-only gather ==========
// Lane layout (round-0-proven): lane covers head hidx=(8*lane)/KH, channels
// (8*lane)%KH..+7. Per edge: per-lane uint4 H-row load (head-replicated lines merge
// in L1) + per-lane EL dword (same-address merge). NO scalar-memory path.
template<int KH, int NCT, bool POOL>
__global__ __launch_bounds__(512, 4) void conv_gemm(
    const int* __restrict__ off, const int* __restrict__ csr_src,
    const float* __restrict__ ELin, const bf16* __restrict__ Hprev,
    const bf16* __restrict__ WT, const float* __restrict__ bias,
    const float* __restrict__ lbe, bf16* __restrict__ Hout,
    float* __restrict__ ELout, const int* __restrict__ batch,
    float* __restrict__ psum)
{
  constexpr int R   = 4*KH;                    // 256 or 384
  constexpr int KS  = R + 32;                  // ind + pad
  constexpr int KA  = KS + KH;                 // 352 or 512
  constexpr int KTS = KS/32, KT = KA/32;
  constexpr int SP  = (KS==288) ? 296 : 424;   // padded ushort stride
  constexpr int OB  = POOL ? (16*68*4) : (16*104*2);
  __shared__ __align__(16) unsigned short Slds[16][SP];
  __shared__ __align__(16) char obuf[OB];
  __shared__ int sbat[16];

  const int wave = threadIdx.x >> 6;           // 0..7
  const int lane = threadIdx.x & 63;
  const int n0 = blockIdx.x*16;

  if (POOL && threadIdx.x < 16) sbat[threadIdx.x] = batch[n0+threadIdx.x];

  const bool act = (8*lane) < R;
  const int hidx = min(3, (8*lane)/KH);
  const unsigned myoff = act ? (unsigned)(((8*lane) % KH) * 2) : 0u;
  const char* Hbase = (const char*)Hprev;

  int ofl = 0;
  if (lane < 3) ofl = off[n0 + wave*2 + lane];

  for (int i=0;i<2;++i){
    const int e0 = __shfl(ofl, i), e1 = __shfl(ofl, i+1);
    float acc[8] = {0.f,0.f,0.f,0.f,0.f,0.f,0.f,0.f};
    float dnl = 0.f;
    for (int base=e0; base<e1; base+=8){
      const int cnt = min(8, e1-base);
      int sreg = (lane < cnt) ? csr_src[base+lane] : 0;
      unsigned sv[8];
      #pragma unroll
      for (int jj=0;jj<8;++jj) sv[jj] = (unsigned)__builtin_amdgcn_readlane(sreg, jj);
      uint4 u[8]; float wl[8];
      #pragma unroll
      for (int jj=0;jj<8;++jj){              // vector loads, 8-16 lines in flight
        u[jj] = act ? *(const uint4*)(Hbase + sv[jj]*(unsigned)(KH*2) + myoff)
                    : make_uint4(0,0,0,0);
        wl[jj] = ELin[sv[jj]*4u + hidx];     // same-addr within head group -> merge
      }
      #pragma unroll
      for (int jj=0;jj<8;++jj){
        float w = (jj < cnt) ? wl[jj] : 0.f;
        dnl += w;
        acc[0] += blo(u[jj].x)*w;  acc[1] += bhi(u[jj].x)*w;
        acc[2] += blo(u[jj].y)*w;  acc[3] += bhi(u[jj].y)*w;
        acc[4] += blo(u[jj].z)*w;  acc[5] += bhi(u[jj].z)*w;
        acc[6] += blo(u[jj].w)*w;  acc[7] += bhi(u[jj].w)*w;
      }
    }
    const float rd = 1.f/(dnl + 1e-16f);
    const int srow = wave*2 + i;
    if (act){
      bf16 st[8];
      #pragma unroll
      for (int t=0;t<8;++t) st[t] = f2b(acc[t]*rd);
      *(bf16x8*)&Slds[srow][8*lane] = *(const bf16x8*)st;
    } else if (8*lane < KS){
      bf16 st[8] = {};
      if (8*lane == R) st[0] = f2b((e1 > e0) ? 1.f : 0.f);  // degree indicator
      *(bf16x8*)&Slds[srow][8*lane] = *(const bf16x8*)st;
    }
  }
  __syncthreads();

  // ---- phase 2: waves 0..NCT-1 each compute one 16-col output tile ----
  const int lm = lane&15, q = lane>>4;
  if (wave < NCT){
    const int ct = wave;
    const bf16* wrow = WT + (size_t)(ct*16+lm)*KA;
    const bf16* srow = Hprev + (size_t)(n0+lm)*KH;
    f32x4 acc2 = {};
    #pragma unroll
    for (int kt=0; kt<KTS; ++kt){
      bf16x8 xfk = *(const bf16x8*)&Slds[lm][kt*32 + q*8];
      bf16x8 wf  = *(const bf16x8*)(wrow + kt*32 + q*8);
      acc2 = __builtin_amdgcn_mfma_f32_16x16x32_bf16(wf, xfk, acc2, 0,0,0);
    }
    #pragma unroll
    for (int kt=KTS; kt<KT; ++kt){
      bf16x8 xfk = *(const bf16x8*)(srow + (kt-KTS)*32 + q*8);
      bf16x8 wf  = *(const bf16x8*)(wrow + kt*32 + q*8);
      acc2 = __builtin_amdgcn_mfma_f32_16x16x32_bf16(wf, xfk, acc2, 0,0,0);
    }
    if (!POOL && ct == NCT-1){
      if (q == 0){                       // next-layer logits -> exp
        float4 e; float l;
        l=acc2[0]+lbe[0]; l=(l>=0.f)?l:0.2f*l; e.x=__expf(fminf(fmaxf(l,-60.f),60.f));
        l=acc2[1]+lbe[1]; l=(l>=0.f)?l:0.2f*l; e.y=__expf(fminf(fmaxf(l,-60.f),60.f));
        l=acc2[2]+lbe[2]; l=(l>=0.f)?l:0.2f*l; e.z=__expf(fminf(fmaxf(l,-60.f),60.f));
        l=acc2[3]+lbe[3]; l=(l>=0.f)?l:0.2f*l; e.w=__expf(fminf(fmaxf(l,-60.f),60.f));
        *(float4*)(ELout + 4*(size_t)(n0+lm)) = e;
      }
    } else {
      const int c = ct*16 + q*4;
      if (POOL){
        float* orow = (float*)obuf + lm*68;
        orow[c]   = acc2[0]+bias[c];   orow[c+1] = acc2[1]+bias[c+1];
        orow[c+2] = acc2[2]+bias[c+2]; orow[c+3] = acc2[3]+bias[c+3];
      } else {
        bf16 st[4] = {f2b(acc2[0]+bias[c]),   f2b(acc2[1]+bias[c+1]),
                      f2b(acc2[2]+bias[c+2]), f2b(acc2[3]+bias[c+3])};
        *(uint2*)((unsigned short*)obuf + lm*104 + c) = *(const uint2*)st;
      }
    }
  }
  __syncthreads();

  if (!POOL){
    const int t = threadIdx.x;
    if (t < 192){                        // coalesced 16x96 bf16 tile store
      const int r = t/12, ch = t - r*12;
      uint4 v = *(const uint4*)((const unsigned short*)obuf + r*104 + ch*8);
      *(uint4*)(Hout + (size_t)(n0+r)*96 + ch*8) = v;
    }
  } else {
    if (threadIdx.x < 64){               // fused global-mean-pool (sum; fc divides)
      const float* ob = (const float*)obuf;
      const int c = threadIdx.x;
      int curg = sbat[0]; float a = 0.f;
      #pragma unroll
      for (int i=0;i<16;++i){
        float v = ob[i*68 + c];
        int g = sbat[i];
        if (g != curg){ atomicAdd(&psum[curg*64+c], a); a=0.f; curg=g; }
        a += v;
      }
      atomicAdd(&psum[curg*64+c], a);
    }
  }
}

// ---------------- classifier + log_softmax (unchanged) ----------------
__global__ __launch_bounds__(64) void fc_kernel(const float* __restrict__ psum,
    const int* __restrict__ batch, const float* __restrict__ Wfc,
    const float* __restrict__ bfc, float* __restrict__ out){
  int g = blockIdx.x, t = threadIdx.x;
  __shared__ int sb[2];
  if (t < 2){
    int target = g + t;
    int lo=0, hi=NN;
    while (lo<hi){ int mid=(lo+hi)>>1; if (batch[mid]<target) lo=mid+1; else hi=mid; }
    sb[t]=lo;
  }
  __syncthreads();
  float cnt = (float)(sb[1]-sb[0]);
  __shared__ float p[CC3];
  __shared__ float lg[NOUT];
  p[t] = psum[g*CC3 + t] / fmaxf(cnt, 1.0f);
  __syncthreads();
  if (t < NOUT){
    float a = bfc[t];
    for (int c=0;c<CC3;++c) a += p[c]*Wfc[c*NOUT + t];
    lg[t] = a;
  }
  __syncthreads();
  if (t < NOUT){
    float m = -INFINITY;
    #pragma unroll
    for (int i=0;i<NOUT;++i) m = fmaxf(m, lg[i]);
    float s = 0.f;
    #pragma unroll
    for (int i=0;i<NOUT;++i) s += __expf(lg[i]-m);
    out[g*NOUT + t] = lg[t] - m - __logf(s);
  }
}

extern "C" void kernel_launch(void* const* d_in, const int* in_sizes, int n_in,
                              void* d_out, int out_size, void* d_ws, size_t ws_size,
                              hipStream_t stream) {
  const float* xf    = (const float*)d_in[0];
  const int*   ei    = (const int*)d_in[1];
  const int*   batch = (const int*)d_in[2];
  const float* pWm1  = (const float*)d_in[3];
  const float* pbm1  = (const float*)d_in[4];
  const float* patt1 = (const float*)d_in[5];
  const float* pWs1  = (const float*)d_in[6];
  const float* pbs1  = (const float*)d_in[7];
  const float* pWm2  = (const float*)d_in[8];
  const float* pbm2  = (const float*)d_in[9];
  const float* patt2 = (const float*)d_in[10];
  const float* pWm3  = (const float*)d_in[11];
  const float* pbm3  = (const float*)d_in[12];
  const float* patt3 = (const float*)d_in[13];
  const float* pWs3  = (const float*)d_in[14];
  const float* pbs3  = (const float*)d_in[15];
  const float* pWfc  = (const float*)d_in[16];
  const float* pbfc  = (const float*)d_in[17];

  // ---- workspace layout ----
  char* p = (char*)d_ws;
  auto alloc = [&](size_t bytes)->char*{ char* q = p; p += (bytes + 255) & ~(size_t)255; return q; };
  int*     deg     = (int*)  alloc(NN*sizeof(int));
  int*     off     = (int*)  alloc((NN+1)*sizeof(int));
  int*     cursor  = (int*)  alloc(NN*sizeof(int));
  int*     csr_src = (int*)  alloc(NE*sizeof(int));
  int*     partials= (int*)  alloc(NPART*sizeof(int));
  int*     done    = (int*)  alloc(sizeof(int));
  float*   ELa     = (float*)alloc((size_t)NN*4*sizeof(float));
  float*   ELb     = (float*)alloc((size_t)NN*4*sizeof(float));
  bf16*    xb      = (bf16*) alloc((size_t)NN*64*sizeof(bf16));
  bf16*    H1b     = (bf16*) alloc((size_t)NN*96*sizeof(bf16));
  bf16*    H2b     = (bf16*) alloc((size_t)NN*96*sizeof(bf16));
  float*   psum    = (float*)alloc((size_t)NG*CC3*sizeof(float));
  float*   f2      = (float*)alloc(96*4*sizeof(float));
  float*   f3      = (float*)alloc(96*4*sizeof(float));
  float*   lbv     = (float*)alloc(12*sizeof(float));
  float*   zb      = (float*)alloc(96*sizeof(float));
  bf16*    WTf1    = (bf16*) alloc((size_t)16*64*sizeof(bf16));
  bf16*    WT1     = (bf16*) alloc((size_t)112*352*sizeof(bf16));
  bf16*    WT2     = (bf16*) alloc((size_t)112*512*sizeof(bf16));
  bf16*    WT3     = (bf16*) alloc((size_t)64*512*sizeof(bf16));

  // ---- prologue ----
  PrepA pa;
  pa.Wm1=pWm1; pa.att1=patt1; pa.bm1=pbm1;
  pa.Wm2=pWm2; pa.att2=patt2; pa.bm2=pbm2;
  pa.Wm3=pWm3; pa.att3=patt3; pa.bm3=pbm3;
  pa.bs1=pbs1; pa.f2=f2; pa.f3=f3; pa.lbv=lbv; pa.zb=zb; pa.WTf1=WTf1;
  pa.deg=deg; pa.psum=psum; pa.done=done;
  prep_a_kernel<<<NPART+2, 256, 0, stream>>>(pa);

  PrepB pb;
  pb.Wm1=pWm1; pb.bm1=pbm1; pb.Ws1=pWs1;
  pb.Wm2=pWm2; pb.bm2=pbm2;
  pb.Wm3=pWm3; pb.bm3=pbm3; pb.Ws3=pWs3;
  pb.f2=f2; pb.f3=f3; pb.WT1=WT1; pb.WT2=WT2; pb.WT3=WT3;
  prep_b_kernel<<<(112*352 + 112*512 + 64*512)/256, 256, 0, stream>>>(pb);

  // ---- CSR build ----
  deg_kernel<<<(NE+255)/256, 256, 0, stream>>>(ei, deg);
  scan_part_kernel<<<NPART, 256, 0, stream>>>(deg, partials, done, off);
  scan_final_kernel<<<NPART, 256, 0, stream>>>(deg, partials, off, cursor);
  scatter_kernel<<<(NE+255)/256, 256, 0, stream>>>(ei, cursor, csr_src);

  // ---- layer-1 front: xb (bf16) + EL1 ----
  el1_kernel<<<(NN/16+3)/4, 256, 0, stream>>>(xf, WTf1, lbv, xb, ELa);

  // ---- fused conv+GEMM layers (8 waves/block, 2 nodes per wave) ----
  conv_gemm<64,7,false><<<NN/16, 512, 0, stream>>>(off, csr_src, ELa, xb,  WT1,
                                                   pbs1, lbv+4, H1b, ELb, batch, psum);
  conv_gemm<96,7,false><<<NN/16, 512, 0, stream>>>(off, csr_src, ELb, H1b, WT2,
                                                   zb,   lbv+8, H2b, ELa, batch, psum);
  conv_gemm<96,4,true ><<<NN/16, 512, 0, stream>>>(off, csr_src, ELa, H2b, WT3,
                                                   pbs3, nullptr, nullptr, nullptr, batch, psum);

  // ---- classifier ----
  fc_kernel<<<NG, 64, 0, stream>>>(psum, batch, pWfc, pbfc, (float*)d_out);
}

// Round 6
// 381.098 us; speedup vs baseline: 1.1091x; 1.1091x over previous
//
#include <hip/hip_runtime.h>
#include <hip/hip_bf16.h>
#include <stdint.h>

using bf16 = __hip_bfloat16;
typedef __attribute__((ext_vector_type(8))) short bf16x8;
typedef __attribute__((ext_vector_type(4))) float f32x4;

#define NN 50000
#define NE 400000
#define NG 64
#define FIN 64
#define HID 96
#define CC3 64
#define NOUT 10

#define SCAN_BLOCK 256
#define NPART ((NN + SCAN_BLOCK - 1) / SCAN_BLOCK)   // 196 (<=256)

__device__ __forceinline__ float b2f(bf16 h){ return __bfloat162float(h); }
__device__ __forceinline__ bf16 f2b(float f){ return __float2bfloat16(f); }
__device__ __forceinline__ float blo(unsigned v){ return __uint_as_float(v << 16); }
__device__ __forceinline__ float bhi(unsigned v){ return __uint_as_float(v & 0xFFFF0000u); }

// ============ prep_a: logit folds, folded-logit tile for layer 1, zero fills ========
struct PrepA {
  const float *Wm1,*att1,*bm1,*Wm2,*att2,*bm2,*Wm3,*att3,*bm3,*bs1;
  float *f2,*f3,*lbv,*zb; bf16* WTf1;
  int* deg; float* psum; int* done;
};
__global__ __launch_bounds__(256) void prep_a_kernel(PrepA j){
  int bid = blockIdx.x;
  if (bid == 0){
    for (int i=threadIdx.x; i<96*4; i+=256){
      int k=i>>2, h=i&3; float a=0.f;
      for (int c=0;c<96;++c) a += j.Wm2[k*384 + h*96 + c]*j.att2[h*96+c];
      j.f2[i]=a;
    }
    for (int i=threadIdx.x; i<96*4; i+=256){
      int k=i>>2, h=i&3; float a=0.f;
      for (int c=0;c<64;++c) a += j.Wm3[k*256 + h*64 + c]*j.att3[h*64+c];
      j.f3[i]=a;
    }
    for (int i=threadIdx.x; i<16*64; i+=256){
      int col=i>>6, k=i&63; float a=0.f;
      if (col<4){ for (int c=0;c<96;++c) a += j.Wm1[k*384 + col*96 + c]*j.att1[col*96+c]; }
      j.WTf1[i] = f2b(a);
    }
    if (threadIdx.x < 96) j.zb[threadIdx.x] = 0.f;
    __syncthreads();
    if (threadIdx.x < 4){
      int h = threadIdx.x;
      float l1=0.f,l2=0.f,l3=0.f;
      for (int c=0;c<96;++c) l1 += j.bm1[h*96+c]*j.att1[h*96+c];
      for (int c=0;c<96;++c) l2 += j.bm2[h*96+c]*j.att2[h*96+c];
      for (int c=0;c<64;++c) l3 += j.bm3[h*64+c]*j.att3[h*64+c];
      float e2 = l2;
      for (int k=0;k<96;++k) e2 += j.bs1[k]*j.f2[k*4+h];
      j.lbv[h]=l1; j.lbv[4+h]=e2; j.lbv[8+h]=l3;
    }
  } else if (bid <= NPART){
    int i=(bid-1)*256+threadIdx.x;
    if (i<NN) j.deg[i]=0;
  } else {
    for (int i=threadIdx.x; i<NG*CC3; i+=256) j.psum[i]=0.f;
    if (threadIdx.x==0) *j.done = 0;
  }
}

// ============ prep_b: combined transposed weight matrices (with logit folds) ========
struct PrepB {
  const float *Wm1,*bm1,*Ws1,*Wm2,*bm2,*Wm3,*bm3,*Ws3;
  const float *f2,*f3;
  bf16 *WT1,*WT2,*WT3;
};
__device__ __forceinline__ float w1full(const PrepB& j, int k, int c){
  if (k < 256) return 0.25f*j.Wm1[(k&63)*384 + (k>>6)*96 + c];
  if (k == 256) return 0.25f*(j.bm1[c]+j.bm1[96+c]+j.bm1[192+c]+j.bm1[288+c]);
  if (k < 288) return 0.f;
  return j.Ws1[(k-288)*96 + c];
}
__device__ __forceinline__ float w2full(const PrepB& j, int k, int c){
  if (k < 384){ int kk=k%96, h=k/96; return 0.25f*j.Wm2[kk*384 + h*96 + c]; }
  if (k == 384) return 0.25f*(j.bm2[c]+j.bm2[96+c]+j.bm2[192+c]+j.bm2[288+c]);
  if (k < 416) return 0.f;
  return (k-416==c) ? 1.f : 0.f;
}
__device__ __forceinline__ float w3full(const PrepB& j, int k, int c){
  if (k < 384){ int kk=k%96, h=k/96; return 0.25f*j.Wm3[kk*256 + h*64 + c]; }
  if (k == 384) return 0.25f*(j.bm3[c]+j.bm3[64+c]+j.bm3[128+c]+j.bm3[192+c]);
  if (k < 416) return 0.f;
  return j.Ws3[(k-416)*64 + c];
}
__global__ __launch_bounds__(256) void prep_b_kernel(PrepB j){
  int idx = blockIdx.x*256 + threadIdx.x;
  if (idx < 112*352){
    int col = idx/352, k = idx - col*352;
    float v;
    if (col < 96) v = w1full(j,k,col);
    else if (col < 100){ int h=col-96; float a=0.f;
      for (int c=0;c<96;++c) a += w1full(j,k,c)*j.f2[c*4+h]; v=a; }
    else v = 0.f;
    j.WT1[col*352 + k] = f2b(v);
  } else if (idx < 112*352 + 112*512){
    int r = idx - 112*352;
    int col = r/512, k = r - col*512;
    float v;
    if (col < 96) v = w2full(j,k,col);
    else if (col < 100){ int h=col-96; float a=0.f;
      for (int c=0;c<96;++c) a += w2full(j,k,c)*j.f3[c*4+h]; v=a; }
    else v = 0.f;
    j.WT2[col*512 + k] = f2b(v);
  } else {
    int r = idx - 112*352 - 112*512;
    int col = r/512, k = r - col*512;
    j.WT3[col*512 + k] = f2b(w3full(j,k,col));
  }
}

// ---------------- CSR build (unchanged, proven) ----------------
__global__ void deg_kernel(const int* __restrict__ ei, int* __restrict__ deg){
  int e = blockIdx.x*256 + threadIdx.x;
  if (e < NE) atomicAdd(&deg[ei[NE + e]], 1);
}

__global__ __launch_bounds__(256) void scan_part_kernel(const int* __restrict__ deg,
    int* __restrict__ partials, int* __restrict__ done, int* __restrict__ off){
  __shared__ int ws[4];
  __shared__ int lastflag;
  __shared__ int buf[256];
  int i = blockIdx.x*SCAN_BLOCK + threadIdx.x;
  int v = (i < NN) ? deg[i] : 0;
  int lane = threadIdx.x & 63, w = threadIdx.x >> 6;
  int s = v;
  #pragma unroll
  for (int m=1;m<64;m<<=1) s += __shfl_xor(s,m);
  if (lane==0) ws[w]=s;
  __syncthreads();
  if (threadIdx.x==0){
    int tot = ws[0]+ws[1]+ws[2]+ws[3];
    atomicExch(&partials[blockIdx.x], tot);
    __threadfence();
    int old = atomicAdd(done, 1);
    lastflag = (old == NPART-1) ? 1 : 0;
  }
  __syncthreads();
  if (lastflag){
    int t = threadIdx.x;
    int pv = (t < NPART) ? atomicAdd(&partials[t], 0) : 0;
    buf[t] = pv; __syncthreads();
    for (int st=1; st<256; st<<=1){
      int x = (t>=st) ? buf[t-st] : 0;
      __syncthreads();
      buf[t] += x;
      __syncthreads();
    }
    if (t < NPART) atomicExch(&partials[t], buf[t] - pv);
    if (t == 0) off[NN] = buf[255];
  }
}

__global__ __launch_bounds__(256) void scan_final_kernel(const int* __restrict__ deg,
    const int* __restrict__ partials, int* __restrict__ off, int* __restrict__ cursor){
  __shared__ int buf[256];
  int i = blockIdx.x*SCAN_BLOCK + threadIdx.x;
  int t = threadIdx.x;
  int v = (i<NN) ? deg[i] : 0;
  buf[t] = v; __syncthreads();
  for (int s=1;s<256;s<<=1){
    int x = (t>=s) ? buf[t-s] : 0;
    __syncthreads();
    buf[t] += x;
    __syncthreads();
  }
  int ex = partials[blockIdx.x] + buf[t] - v;
  if (i<NN){ off[i]=ex; cursor[i]=ex; }
}

__global__ void scatter_kernel(const int* __restrict__ ei, int* __restrict__ cursor,
                               int* __restrict__ csr_src){
  int e = blockIdx.x*256 + threadIdx.x;
  if (e < NE){
    int d = ei[NE + e];
    int slot = atomicAdd(&cursor[d], 1);
    csr_src[slot] = ei[e];
  }
}

// ============ layer-1 front: bf16 copy of x + EL1 via folded-logit MFMA =============
__global__ __launch_bounds__(256) void el1_kernel(const float* __restrict__ x,
    const bf16* __restrict__ WTf1, const float* __restrict__ lbv,
    bf16* __restrict__ xb, float* __restrict__ EL)
{
  const int wave = threadIdx.x>>6, lane = threadIdx.x&63;
  const int tile = blockIdx.x*4 + wave;
  if (tile >= NN/16) return;
  const int lm = lane&15, q = lane>>4;
  const size_t row = (size_t)tile*16 + lm;
  bf16x8 xf[2];
  #pragma unroll
  for (int kt=0;kt<2;++kt){
    float4 a0 = *(const float4*)(x + row*64 + kt*32 + q*8);
    float4 a1 = *(const float4*)(x + row*64 + kt*32 + q*8 + 4);
    bf16 t[8] = {f2b(a0.x),f2b(a0.y),f2b(a0.z),f2b(a0.w),
                 f2b(a1.x),f2b(a1.y),f2b(a1.z),f2b(a1.w)};
    xf[kt] = *(const bf16x8*)t;
    *(bf16x8*)(xb + row*64 + kt*32 + q*8) = xf[kt];
  }
  f32x4 acc = {};
  #pragma unroll
  for (int kt=0;kt<2;++kt){
    bf16x8 wf = *(const bf16x8*)(WTf1 + (size_t)lm*64 + kt*32 + q*8);
    acc = __builtin_amdgcn_mfma_f32_16x16x32_bf16(wf, xf[kt], acc, 0,0,0);
  }
  if (q==0){
    float4 e; float l;
    l=acc[0]+lbv[0]; l=(l>=0.f)?l:0.2f*l; e.x=__expf(fminf(fmaxf(l,-60.f),60.f));
    l=acc[1]+lbv[1]; l=(l>=0.f)?l:0.2f*l; e.y=__expf(fminf(fmaxf(l,-60.f),60.f));
    l=acc[2]+lbv[2]; l=(l>=0.f)?l:0.2f*l; e.z=__expf(fminf(fmaxf(l,-60.f),60.f));
    l=acc[3]+lbv[3]; l=(l>=0.f)?l:0.2f*l; e.w=__expf(fminf(fmaxf(l,-60.f),60.f));
    *(float4*)(EL + 4*row) = e;
  }
}

// ============ fused conv + GEMM with BULK-STAGED gather ==============================
// Per 16-node block: stage the edge slab's source rows into LDS cooperatively
// (2 threads/row, coalesced uint4 loads -> hundreds of independent requests in
// flight), plus per-edge float4 of head weights. The weighted sum then runs on
// LDS reads (same-row broadcast, conflict-free) -> no per-wave serial VMEM chains.
template<int KH, int NCT, bool POOL>
__global__ __launch_bounds__(256, 3) void conv_gemm(
    const int* __restrict__ off, const int* __restrict__ csr_src,
    const float* __restrict__ ELin, const bf16* __restrict__ Hprev,
    const bf16* __restrict__ WT, const float* __restrict__ bias,
    const float* __restrict__ lbe, bf16* __restrict__ Hout,
    float* __restrict__ ELout, const int* __restrict__ batch,
    float* __restrict__ psum)
{
  constexpr int R    = 4*KH;                   // 256 or 384
  constexpr int KS   = R + 32;                 // ind + pad
  constexpr int KA   = KS + KH;                // 352 or 512
  constexpr int KTS  = KS/32, KT = KA/32;
  constexpr int SP   = (KS==288) ? 296 : 424;  // Slds ushort stride (16B-aligned)
  constexpr int OB   = POOL ? (16*68*4) : (16*104*2);
  constexpr int SLAB = 128;                    // staged edges per round
  constexpr int HS   = KH + 8;                 // Hlds ushort stride (16B-aligned)
  constexpr int CPT  = KH/16;                  // uint4 per half-row: 4 or 6
  __shared__ __align__(16) unsigned short Hlds[SLAB][HS];
  __shared__ __align__(16) float wlds[SLAB][4];
  __shared__ __align__(16) unsigned short Slds[16][SP];
  __shared__ __align__(16) char obuf[OB];
  __shared__ int sbat[16];

  const int tid  = threadIdx.x;
  const int wave = tid >> 6, lane = tid & 63;
  const int n0 = blockIdx.x*16;

  if (POOL && tid < 16) sbat[tid] = batch[n0+tid];

  const int eb   = off[n0];
  const int ecnt = off[n0+16] - eb;

  int ofl = 0;
  if (lane < 5) ofl = off[n0 + wave*4 + lane];

  const bool act = (8*lane) < R;
  const int hidx = min(3, (8*lane)/KH);
  const int myc  = act ? ((8*lane) % KH) : 0;

  float acc[4][8] = {};
  float dnl[4] = {0.f,0.f,0.f,0.f};

  for (int sb=0; sb<ecnt; sb+=SLAB){
    const int cnt = min(SLAB, ecnt - sb);
    if (sb) __syncthreads();                   // Hlds/wlds reuse
    // ---- bulk stage: 2 threads per edge-row, fully parallel loads ----
    {
      const int r = tid >> 1, hf = tid & 1;
      if (r < cnt){
        const unsigned id = (unsigned)csr_src[eb + sb + r];
        const bf16* srcp = Hprev + (size_t)id*KH + hf*(KH/2);
        #pragma unroll
        for (int c=0; c<CPT; ++c){
          uint4 v = *(const uint4*)(srcp + c*8);
          *(uint4*)&Hlds[r][hf*(KH/2) + c*8] = v;
        }
      }
      if (tid < cnt){
        const unsigned id2 = (unsigned)csr_src[eb + sb + tid];
        *(float4*)&wlds[tid][0] = *(const float4*)(ELin + 4*(size_t)id2);
      }
    }
    __syncthreads();
    // ---- per-wave weighted sums from LDS (4 nodes per wave) ----
    #pragma unroll
    for (int ii=0; ii<4; ++ii){
      int jlo = __shfl(ofl, ii)   - eb - sb;
      int jhi = __shfl(ofl, ii+1) - eb - sb;
      jlo = max(jlo, 0); jhi = min(jhi, cnt);
      for (int j=jlo; j<jhi; ++j){
        const uint4 hv = *(const uint4*)&Hlds[j][myc];
        const float w  = wlds[j][hidx];
        dnl[ii] += w;
        acc[ii][0] += blo(hv.x)*w;  acc[ii][1] += bhi(hv.x)*w;
        acc[ii][2] += blo(hv.y)*w;  acc[ii][3] += bhi(hv.y)*w;
        acc[ii][4] += blo(hv.z)*w;  acc[ii][5] += bhi(hv.z)*w;
        acc[ii][6] += blo(hv.w)*w;  acc[ii][7] += bhi(hv.w)*w;
      }
    }
  }

  // ---- normalize + write S rows ----
  #pragma unroll
  for (int ii=0; ii<4; ++ii){
    const int srow = wave*4 + ii;
    const float rd = 1.f/(dnl[ii] + 1e-16f);
    if (act){
      bf16 st[8];
      #pragma unroll
      for (int t=0;t<8;++t) st[t] = f2b(acc[ii][t]*rd);
      *(bf16x8*)&Slds[srow][8*lane] = *(const bf16x8*)st;
    } else if (8*lane < KS){
      const int e0n = __shfl(ofl, ii), e1n = __shfl(ofl, ii+1);
      bf16 st[8] = {};
      if (8*lane == R) st[0] = f2b((e1n > e0n) ? 1.f : 0.f);  // degree indicator
      *(bf16x8*)&Slds[srow][8*lane] = *(const bf16x8*)st;
    }
  }
  __syncthreads();

  // ---- phase 2: A-fragments hoisted, waves loop over 16-col output tiles ----
  const int lm = lane&15, q = lane>>4;
  bf16x8 xf[KT];
  #pragma unroll
  for (int kt=0; kt<KTS; ++kt)
    xf[kt] = *(const bf16x8*)&Slds[lm][kt*32 + q*8];
  {
    const bf16* srow2 = Hprev + (size_t)(n0+lm)*KH;
    #pragma unroll
    for (int kt=KTS; kt<KT; ++kt)
      xf[kt] = *(const bf16x8*)(srow2 + (kt-KTS)*32 + q*8);
  }

  for (int ct = wave; ct < NCT; ct += 4){
    const bf16* wrow = WT + (size_t)(ct*16+lm)*KA;
    f32x4 acc2 = {};
    #pragma unroll
    for (int kt=0; kt<KT; ++kt){
      bf16x8 wf = *(const bf16x8*)(wrow + kt*32 + q*8);
      acc2 = __builtin_amdgcn_mfma_f32_16x16x32_bf16(wf, xf[kt], acc2, 0,0,0);
    }
    if (!POOL && ct == NCT-1){
      if (q == 0){                       // next-layer logits -> exp
        float4 e; float l;
        l=acc2[0]+lbe[0]; l=(l>=0.f)?l:0.2f*l; e.x=__expf(fminf(fmaxf(l,-60.f),60.f));
        l=acc2[1]+lbe[1]; l=(l>=0.f)?l:0.2f*l; e.y=__expf(fminf(fmaxf(l,-60.f),60.f));
        l=acc2[2]+lbe[2]; l=(l>=0.f)?l:0.2f*l; e.z=__expf(fminf(fmaxf(l,-60.f),60.f));
        l=acc2[3]+lbe[3]; l=(l>=0.f)?l:0.2f*l; e.w=__expf(fminf(fmaxf(l,-60.f),60.f));
        *(float4*)(ELout + 4*(size_t)(n0+lm)) = e;
      }
    } else {
      const int c = ct*16 + q*4;
      if (POOL){
        float* orow = (float*)obuf + lm*68;
        orow[c]   = acc2[0]+bias[c];   orow[c+1] = acc2[1]+bias[c+1];
        orow[c+2] = acc2[2]+bias[c+2]; orow[c+3] = acc2[3]+bias[c+3];
      } else {
        bf16 st[4] = {f2b(acc2[0]+bias[c]),   f2b(acc2[1]+bias[c+1]),
                      f2b(acc2[2]+bias[c+2]), f2b(acc2[3]+bias[c+3])};
        *(uint2*)((unsigned short*)obuf + lm*104 + c) = *(const uint2*)st;
      }
    }
  }
  __syncthreads();

  if (!POOL){
    const int t = threadIdx.x;
    if (t < 192){                        // coalesced 16x96 bf16 tile store
      const int r = t/12, ch = t - r*12;
      uint4 v = *(const uint4*)((const unsigned short*)obuf + r*104 + ch*8);
      *(uint4*)(Hout + (size_t)(n0+r)*96 + ch*8) = v;
    }
  } else {
    if (threadIdx.x < 64){               // fused global-mean-pool (sum; fc divides)
      const float* ob = (const float*)obuf;
      const int c = threadIdx.x;
      int curg = sbat[0]; float a = 0.f;
      #pragma unroll
      for (int i=0;i<16;++i){
        float v = ob[i*68 + c];
        int g = sbat[i];
        if (g != curg){ atomicAdd(&psum[curg*64+c], a); a=0.f; curg=g; }
        a += v;
      }
      atomicAdd(&psum[curg*64+c], a);
    }
  }
}

// ---------------- classifier + log_softmax (unchanged) ----------------
__global__ __launch_bounds__(64) void fc_kernel(const float* __restrict__ psum,
    const int* __restrict__ batch, const float* __restrict__ Wfc,
    const float* __restrict__ bfc, float* __restrict__ out){
  int g = blockIdx.x, t = threadIdx.x;
  __shared__ int sb[2];
  if (t < 2){
    int target = g + t;
    int lo=0, hi=NN;
    while (lo<hi){ int mid=(lo+hi)>>1; if (batch[mid]<target) lo=mid+1; else hi=mid; }
    sb[t]=lo;
  }
  __syncthreads();
  float cnt = (float)(sb[1]-sb[0]);
  __shared__ float p[CC3];
  __shared__ float lg[NOUT];
  p[t] = psum[g*CC3 + t] / fmaxf(cnt, 1.0f);
  __syncthreads();
  if (t < NOUT){
    float a = bfc[t];
    for (int c=0;c<CC3;++c) a += p[c]*Wfc[c*NOUT + t];
    lg[t] = a;
  }
  __syncthreads();
  if (t < NOUT){
    float m = -INFINITY;
    #pragma unroll
    for (int i=0;i<NOUT;++i) m = fmaxf(m, lg[i]);
    float s = 0.f;
    #pragma unroll
    for (int i=0;i<NOUT;++i) s += __expf(lg[i]-m);
    out[g*NOUT + t] = lg[t] - m - __logf(s);
  }
}

extern "C" void kernel_launch(void* const* d_in, const int* in_sizes, int n_in,
                              void* d_out, int out_size, void* d_ws, size_t ws_size,
                              hipStream_t stream) {
  const float* xf    = (const float*)d_in[0];
  const int*   ei    = (const int*)d_in[1];
  const int*   batch = (const int*)d_in[2];
  const float* pWm1  = (const float*)d_in[3];
  const float* pbm1  = (const float*)d_in[4];
  const float* patt1 = (const float*)d_in[5];
  const float* pWs1  = (const float*)d_in[6];
  const float* pbs1  = (const float*)d_in[7];
  const float* pWm2  = (const float*)d_in[8];
  const float* pbm2  = (const float*)d_in[9];
  const float* patt2 = (const float*)d_in[10];
  const float* pWm3  = (const float*)d_in[11];
  const float* pbm3  = (const float*)d_in[12];
  const float* patt3 = (const float*)d_in[13];
  const float* pWs3  = (const float*)d_in[14];
  const float* pbs3  = (const float*)d_in[15];
  const float* pWfc  = (const float*)d_in[16];
  const float* pbfc  = (const float*)d_in[17];

  // ---- workspace layout ----
  char* p = (char*)d_ws;
  auto alloc = [&](size_t bytes)->char*{ char* q = p; p += (bytes + 255) & ~(size_t)255; return q; };
  int*     deg     = (int*)  alloc(NN*sizeof(int));
  int*     off     = (int*)  alloc((NN+1)*sizeof(int));
  int*     cursor  = (int*)  alloc(NN*sizeof(int));
  int*     csr_src = (int*)  alloc(NE*sizeof(int));
  int*     partials= (int*)  alloc(NPART*sizeof(int));
  int*     done    = (int*)  alloc(sizeof(int));
  float*   ELa     = (float*)alloc((size_t)NN*4*sizeof(float));
  float*   ELb     = (float*)alloc((size_t)NN*4*sizeof(float));
  bf16*    xb      = (bf16*) alloc((size_t)NN*64*sizeof(bf16));
  bf16*    H1b     = (bf16*) alloc((size_t)NN*96*sizeof(bf16));
  bf16*    H2b     = (bf16*) alloc((size_t)NN*96*sizeof(bf16));
  float*   psum    = (float*)alloc((size_t)NG*CC3*sizeof(float));
  float*   f2      = (float*)alloc(96*4*sizeof(float));
  float*   f3      = (float*)alloc(96*4*sizeof(float));
  float*   lbv     = (float*)alloc(12*sizeof(float));
  float*   zb      = (float*)alloc(96*sizeof(float));
  bf16*    WTf1    = (bf16*) alloc((size_t)16*64*sizeof(bf16));
  bf16*    WT1     = (bf16*) alloc((size_t)112*352*sizeof(bf16));
  bf16*    WT2     = (bf16*) alloc((size_t)112*512*sizeof(bf16));
  bf16*    WT3     = (bf16*) alloc((size_t)64*512*sizeof(bf16));

  // ---- prologue ----
  PrepA pa;
  pa.Wm1=pWm1; pa.att1=patt1; pa.bm1=pbm1;
  pa.Wm2=pWm2; pa.att2=patt2; pa.bm2=pbm2;
  pa.Wm3=pWm3; pa.att3=patt3; pa.bm3=pbm3;
  pa.bs1=pbs1; pa.f2=f2; pa.f3=f3; pa.lbv=lbv; pa.zb=zb; pa.WTf1=WTf1;
  pa.deg=deg; pa.psum=psum; pa.done=done;
  prep_a_kernel<<<NPART+2, 256, 0, stream>>>(pa);

  PrepB pb;
  pb.Wm1=pWm1; pb.bm1=pbm1; pb.Ws1=pWs1;
  pb.Wm2=pWm2; pb.bm2=pbm2;
  pb.Wm3=pWm3; pb.bm3=pbm3; pb.Ws3=pWs3;
  pb.f2=f2; pb.f3=f3; pb.WT1=WT1; pb.WT2=WT2; pb.WT3=WT3;
  prep_b_kernel<<<(112*352 + 112*512 + 64*512)/256, 256, 0, stream>>>(pb);

  // ---- CSR build ----
  deg_kernel<<<(NE+255)/256, 256, 0, stream>>>(ei, deg);
  scan_part_kernel<<<NPART, 256, 0, stream>>>(deg, partials, done, off);
  scan_final_kernel<<<NPART, 256, 0, stream>>>(deg, partials, off, cursor);
  scatter_kernel<<<(NE+255)/256, 256, 0, stream>>>(ei, cursor, csr_src);

  // ---- layer-1 front: xb (bf16) + EL1 ----
  el1_kernel<<<(NN/16+3)/4, 256, 0, stream>>>(xf, WTf1, lbv, xb, ELa);

  // ---- fused conv+GEMM layers (bulk-staged gather, 256 thr / 16 nodes) ----
  conv_gemm<64,7,false><<<NN/16, 256, 0, stream>>>(off, csr_src, ELa, xb,  WT1,
                                                   pbs1, lbv+4, H1b, ELb, batch, psum);
  conv_gemm<96,7,false><<<NN/16, 256, 0, stream>>>(off, csr_src, ELb, H1b, WT2,
                                                   zb,   lbv+8, H2b, ELa, batch, psum);
  conv_gemm<96,4,true ><<<NN/16, 256, 0, stream>>>(off, csr_src, ELa, H2b, WT3,
                                                   pbs3, nullptr, nullptr, nullptr, batch, psum);

  // ---- classifier ----
  fc_kernel<<<NG, 64, 0, stream>>>(psum, batch, pWfc, pbfc, (float*)d_out);
}